// Round 6
// baseline (511.995 us; speedup 1.0000x reference)
//
#include <hip/hip_runtime.h>
#include <math.h>

#ifndef M_PI
#define M_PI 3.14159265358979323846
#endif

// ---------------- constants ----------------
#define NSIDE 128
#define NVOX  2097152          // 128^3
#define KBINS 100
#define NFIELDS 16             // 8 pred + 8 target
#define NORMF (27.0f / 2097152.0f)   // LPIX^3 / N^3
#define FSTRIDE ((size_t)65 * 16384) // float2 elems per field
#define NBLK_XBIN (65 * 4 * NFIELDS) // 4160 pass-X blocks

// A layout (float2 units), per field:
//   elem(kz, p, x) = kz*16384 + (p>>3)*1024 + x*8 + (p&7)
// p = y-slot (ky slot order), x = spatial x, kz = 0..64.
// zy writes: per store instr, 8x 64B contiguous segments. x_bin reads: per
// load instr, 512B contiguous.

// ws layout (bytes)
#define WS_SUMS_OFF   0                       // float[16*101]
#define WS_CNT_OFF    6464                    // int[101]
#define WS_CTR_OFF    7936                    // int[1] last-block counter
#define WS_OCT_OFF    8192                    // uint8[65*65*65], kz-major: oct[c][a][b]
#define WS_TRANS_OFF  282880                  // float2[16 * FSTRIDE] = 136.3 MB

// ---------------- exact numpy binning replication (fp64) ----------------
__device__ __forceinline__ double bin_edge(int i, double start, double step, double stop) {
    if (i == 100) return stop;
    return __dadd_rn(__dmul_rn((double)i, step), start);
}

__device__ __forceinline__ void bin_params(double* start, double* step, double* stop) {
    const double inv   = 1.0 / 384.0;
    const double twopi = 2.0 * M_PI;
    double k1 = __dmul_rn(twopi, __dmul_rn(1.0, inv));
    *start = sqrt(__dadd_rn(__dadd_rn(0.0, 0.0), __dmul_rn(k1, k1)));
    double k64 = __dmul_rn(twopi, __dmul_rn(-64.0, inv));
    double s64 = __dmul_rn(k64, k64);
    *stop = sqrt(__dadd_rn(__dadd_rn(s64, s64), s64));
    *step = (*stop - *start) / 100.0;
}

__device__ int compute_bin(int ix, int iy, int iz) {
    const double inv   = 1.0 / 384.0;
    const double twopi = 2.0 * M_PI;
    double fx = (double)(ix < 64 ? ix : ix - 128);
    double fy = (double)(iy < 64 ? iy : iy - 128);
    double fz = (double)(iz < 64 ? iz : iz - 128);
    double kx = __dmul_rn(twopi, __dmul_rn(fx, inv));
    double ky = __dmul_rn(twopi, __dmul_rn(fy, inv));
    double kz = __dmul_rn(twopi, __dmul_rn(fz, inv));
    double sq = __dadd_rn(__dadd_rn(__dmul_rn(kx, kx), __dmul_rn(ky, ky)), __dmul_rn(kz, kz));
    double kmag = sqrt(sq);
    if (!(kmag > 0.0)) return 100;                   // DC -> dropped bin
    double start, step, stop;
    bin_params(&start, &step, &stop);
    double t = (kmag - start) / step;
    int c = (int)floor(t);
    if (c < -1) c = -1;
    if (c > 100) c = 100;
    while (c < 100 && kmag >= bin_edge(c + 1, start, step, stop)) ++c;
    while (c >= 0 && kmag < bin_edge(c, start, step, stop)) --c;
    if (c < 0) c = 0;
    if (c > 99) c = 99;
    return c;
}

// ---------------- bit reversal helpers ----------------
__device__ __forceinline__ int br3(int v) { return ((v & 1) << 2) | (v & 2) | ((v >> 2) & 1); }
__device__ __forceinline__ int br4(int v) {
    return ((v & 1) << 3) | ((v & 2) << 1) | ((v & 4) >> 1) | ((v & 8) >> 3);
}

__device__ __forceinline__ float2 f2add(float2 a, float2 b) { return make_float2(a.x + b.x, a.y + b.y); }
__device__ __forceinline__ float2 f2sub(float2 a, float2 b) { return make_float2(a.x - b.x, a.y - b.y); }
__device__ __forceinline__ float2 cmul(float2 a, float2 w) {
    return make_float2(a.x * w.x - a.y * w.y, a.x * w.y + a.y * w.x);
}
__device__ __forceinline__ float2 twid(float r) {   // e^{2*pi*i*r}, r in revolutions
    return make_float2(__builtin_amdgcn_cosf(r), __builtin_amdgcn_sinf(r));
}

// ---------------- R=16 "slot" 128-pt FFT (lane m holds n = m + 8j) ----------------
// Output: position n = m+8j holds X[bitrev7(n)] -> k = (br3(m)<<4) | br4(j).
__device__ __forceinline__ void fft128_r16(float2 r[16], int m) {
    const float fm = (float)m;
#pragma unroll
    for (int j = 0; j < 8; ++j) {
        float2 W = twid(-(fm + 8.0f * (float)j) * (1.0f / 128.0f));
        float2 a = r[j], b = r[j + 8];
        r[j]     = f2add(a, b);
        r[j + 8] = cmul(f2sub(a, b), W);
    }
#pragma unroll
    for (int j = 0; j < 4; ++j) {
        float2 W = twid(-(fm + 8.0f * (float)j) * (1.0f / 64.0f));
#pragma unroll
        for (int half = 0; half < 16; half += 8) {
            float2 a = r[half + j], b = r[half + j + 4];
            r[half + j]     = f2add(a, b);
            r[half + j + 4] = cmul(f2sub(a, b), W);
        }
    }
#pragma unroll
    for (int j = 0; j < 2; ++j) {
        float2 W = twid(-(fm + 8.0f * (float)j) * (1.0f / 32.0f));
#pragma unroll
        for (int q = 0; q < 16; q += 4) {
            float2 a = r[q + j], b = r[q + j + 2];
            r[q + j]     = f2add(a, b);
            r[q + j + 2] = cmul(f2sub(a, b), W);
        }
    }
    {
        float2 W = twid(-fm * (1.0f / 16.0f));
#pragma unroll
        for (int q = 0; q < 16; q += 2) {
            float2 a = r[q], b = r[q + 1];
            r[q]     = f2add(a, b);
            r[q + 1] = cmul(f2sub(a, b), W);
        }
    }
#pragma unroll
    for (int h = 4; h >= 2; h >>= 1) {
        bool hi = (m & h) != 0;
        float2 W = twid(-(float)(m & (h - 1)) / (float)(2 * h));
#pragma unroll
        for (int j = 0; j < 16; ++j) {
            float2 x = r[j];
            float2 v = make_float2(__shfl_xor(x.x, h, 64), __shfl_xor(x.y, h, 64));
            float2 s = f2add(x, v);
            float2 d = cmul(f2sub(v, x), W);
            r[j] = hi ? d : s;
        }
    }
    {
        bool hi = (m & 1) != 0;
#pragma unroll
        for (int j = 0; j < 16; ++j) {
            float2 x = r[j];
            float2 v = make_float2(__shfl_xor(x.x, 1, 64), __shfl_xor(x.y, 1, 64));
            r[j] = hi ? f2sub(v, x) : f2add(x, v);
        }
    }
}

// ---------------- "contiguous" 128-pt FFT (lane m holds n = 16m + j) ----------------
// Output: position (m,j) holds X[8*br4(j) + br3(m)]. Zero sin/cos.
__device__ __forceinline__ void fft128_c16(float2 r[16], int m) {
    const float S2 = 0.70710678118654752f;
    // ---- h=64: partner m^4; W = Wm[m&3] * e^{-2pi i j/128}
    {
        int q = m & 3;
        float2 Wm = make_float2(q == 0 ? 1.f : (q == 1 ? S2 : (q == 2 ? 0.f : -S2)),
                                q == 0 ? 0.f : (q == 2 ? -1.f : -S2));
        bool hi = (m & 4) != 0;
        const float2 C[16] = {
            {1.f,0.f},{0.99879546f,-0.04906767f},{0.99518473f,-0.09801714f},
            {0.98917651f,-0.14673047f},{0.98078528f,-0.19509032f},{0.97003125f,-0.24298018f},
            {0.95694034f,-0.29028468f},{0.94154407f,-0.33688985f},{0.92387953f,-0.38268343f},
            {0.90398929f,-0.42755509f},{0.88192126f,-0.47139674f},{0.85772861f,-0.51410274f},
            {0.83146961f,-0.55557023f},{0.80320753f,-0.59569930f},{0.77301045f,-0.63439328f},
            {0.74095113f,-0.67155895f} };
#pragma unroll
        for (int j = 0; j < 16; ++j) {
            float2 x = r[j];
            float2 v = make_float2(__shfl_xor(x.x, 4, 64), __shfl_xor(x.y, 4, 64));
            float2 s = f2add(x, v);
            float2 d = cmul(cmul(f2sub(v, x), Wm), C[j]);
            r[j] = hi ? d : s;
        }
    }
    // ---- h=32: partner m^2; W = (m&1 ? -i : 1) * e^{-2pi i j/64}
    {
        bool w = (m & 1) != 0;
        bool hi = (m & 2) != 0;
        const float2 C[16] = {
            {1.f,0.f},{0.99518473f,-0.09801714f},{0.98078528f,-0.19509032f},
            {0.95694034f,-0.29028468f},{0.92387953f,-0.38268343f},{0.88192126f,-0.47139674f},
            {0.83146961f,-0.55557023f},{0.77301045f,-0.63439328f},{S2,-S2},
            {0.63439328f,-0.77301045f},{0.55557023f,-0.83146961f},{0.47139674f,-0.88192126f},
            {0.38268343f,-0.92387953f},{0.29028468f,-0.95694034f},{0.19509032f,-0.98078528f},
            {0.09801714f,-0.99518473f} };
#pragma unroll
        for (int j = 0; j < 16; ++j) {
            float2 x = r[j];
            float2 v = make_float2(__shfl_xor(x.x, 2, 64), __shfl_xor(x.y, 2, 64));
            float2 s = f2add(x, v);
            float2 d = f2sub(v, x);
            d = w ? make_float2(d.y, -d.x) : d;
            d = cmul(d, C[j]);
            r[j] = hi ? d : s;
        }
    }
    // ---- h=16: partner m^1; W = e^{-2pi i j/32}
    {
        bool hi = (m & 1) != 0;
        const float2 C[16] = {
            {1.f,0.f},{0.98078528f,-0.19509032f},{0.92387953f,-0.38268343f},
            {0.83146961f,-0.55557023f},{S2,-S2},{0.55557023f,-0.83146961f},
            {0.38268343f,-0.92387953f},{0.19509032f,-0.98078528f},{0.f,-1.f},
            {-0.19509032f,-0.98078528f},{-0.38268343f,-0.92387953f},{-0.55557023f,-0.83146961f},
            {-S2,-S2},{-0.83146961f,-0.55557023f},{-0.92387953f,-0.38268343f},
            {-0.98078528f,-0.19509032f} };
#pragma unroll
        for (int j = 0; j < 16; ++j) {
            float2 x = r[j];
            float2 v = make_float2(__shfl_xor(x.x, 1, 64), __shfl_xor(x.y, 1, 64));
            float2 s = f2add(x, v);
            float2 d = cmul(f2sub(v, x), C[j]);
            r[j] = hi ? d : s;
        }
    }
    // ---- h=8
    {
        const float2 C[8] = {
            {1.f,0.f},{0.92387953f,-0.38268343f},{S2,-S2},{0.38268343f,-0.92387953f},
            {0.f,-1.f},{-0.38268343f,-0.92387953f},{-S2,-S2},{-0.92387953f,-0.38268343f} };
#pragma unroll
        for (int j = 0; j < 8; ++j) {
            float2 a = r[j], b = r[j + 8];
            r[j]     = f2add(a, b);
            r[j + 8] = cmul(f2sub(a, b), C[j]);
        }
    }
    // ---- h=4
    {
        const float2 C[4] = { {1.f,0.f},{S2,-S2},{0.f,-1.f},{-S2,-S2} };
#pragma unroll
        for (int q = 0; q < 16; q += 8)
#pragma unroll
            for (int j = 0; j < 4; ++j) {
                float2 a = r[q + j], b = r[q + j + 4];
                r[q + j]     = f2add(a, b);
                r[q + j + 4] = cmul(f2sub(a, b), C[j]);
            }
    }
    // ---- h=2
    {
#pragma unroll
        for (int q = 0; q < 16; q += 4) {
            { float2 a = r[q], b = r[q + 2]; r[q] = f2add(a, b); r[q + 2] = f2sub(a, b); }
            { float2 a = r[q + 1], b = r[q + 3]; float2 d = f2sub(a, b);
              r[q + 1] = f2add(a, b); r[q + 3] = make_float2(d.y, -d.x); }
        }
    }
    // ---- h=1
    {
#pragma unroll
        for (int q = 0; q < 16; q += 2) {
            float2 a = r[q], b = r[q + 1];
            r[q] = f2add(a, b); r[q + 1] = f2sub(a, b);
        }
    }
}

// ---------------- fused Z+Y (y>=1) and oct-table (y==0) kernel ----------------
// y==0: oct table + weighted mode counts (concurrent with zy planes).
// y>=1: R3's verified zy body, verbatim (512 thr, 2-iter phases).
__global__ __launch_bounds__(512, 4) void k_zy_oct(const float* __restrict__ pred,
                                                   const float* __restrict__ target,
                                                   float2* __restrict__ A,
                                                   unsigned char* __restrict__ oct,
                                                   int* __restrict__ counts) {
    __shared__ float2 lds[65][132];
    int t = threadIdx.x;

    if (blockIdx.y == 0) {
        // -------- oct path --------
        int* lcnt = (int*)&lds[0][0];            // 4*104 ints, aliased into lds
        for (int j = t; j < 4 * 104; j += 512) lcnt[j] = 0;
        __syncthreads();
        for (int idx = blockIdx.x * 512 + t; idx < 65 * 65 * 65; idx += 128 * 512) {
            int c = idx % 65;
            int r = idx / 65;
            int b = r % 65;
            int a = r / 65;
            int id = compute_bin(a, b, c);
            oct[c * 4225 + a * 65 + b] = (unsigned char)id;
            if (id < 100) {
                int w = ((a == 0 || a == 64) ? 1 : 2) *
                        ((b == 0 || b == 64) ? 1 : 2) *
                        ((c == 0 || c == 64) ? 1 : 2);
                atomicAdd(&lcnt[(t & 3) * 104 + id], w);
            }
        }
        __syncthreads();
        if (t < 101) {
            int tot = lcnt[t] + lcnt[104 + t] + lcnt[208 + t] + lcnt[312 + t];
            if (tot) atomicAdd(&counts[t], tot);
        }
        return;
    }

    // -------- zy path (R3 verbatim) --------
    int m = t & 7, row = t >> 3;          // 64 groups
    int x = blockIdx.x;
    int f = blockIdx.y - 1;
    const float* in = (f < 8) ? (pred + (size_t)f * NVOX)
                              : (target + (size_t)(f - 8) * NVOX);

    // Phase 1: z-FFTs (contiguous-lane variant), decimate kz<=64
    int b3 = br3(m);
#pragma unroll
    for (int y0 = 0; y0 < 128; y0 += 64) {
        int y = y0 + row;
        const float4* s4 = reinterpret_cast<const float4*>(
            in + (size_t)x * 16384 + (size_t)y * 128 + 16 * m);
        float2 r[16];
#pragma unroll
        for (int q = 0; q < 4; ++q) {
            float4 v = s4[q];
            r[4 * q + 0] = make_float2(v.x, 0.f);
            r[4 * q + 1] = make_float2(v.y, 0.f);
            r[4 * q + 2] = make_float2(v.z, 0.f);
            r[4 * q + 3] = make_float2(v.w, 0.f);
        }
        fft128_c16(r, m);
        // kz(m,j) = 8*br4(j) + br3(m); kz<=64 <=> j even, plus (m=0,j=1)->kz=64
#pragma unroll
        for (int j = 0; j < 16; j += 2) {
            int kz = 8 * br4(j) + b3;
            lds[kz][y] = r[j];
        }
        if (m == 0) lds[64][y] = r[1];
    }
    __syncthreads();                      // LDS plane [65][128] complete

    // Phase 2: y-FFTs from LDS, write A (tiled layout)
    float2* basef = A + (size_t)f * FSTRIDE + (size_t)x * 8;
#pragma unroll
    for (int k0 = 0; k0 < 128; k0 += 64) {
        int kz = k0 + row;
        if (kz <= 64) {
            float2 r[16];
#pragma unroll
            for (int j = 0; j < 16; ++j) r[j] = lds[kz][m + 8 * j];
            fft128_r16(r, m);
            float2* dst = basef + (size_t)kz * 16384;
            // slot p = m+8j -> offset (p>>3)*1024 + (p&7) = j*1024 + m
#pragma unroll
            for (int j = 0; j < 16; ++j) dst[j * 1024 + m] = r[j];
        }
    }
}

// ---------------- Pass X (R3 verbatim) + fused last-block finalize ----------------
__global__ __launch_bounds__(256, 6) void k_fft_x_bin(const float2* __restrict__ A,
                                                      const unsigned char* __restrict__ oct,
                                                      float* __restrict__ sums,
                                                      const int* __restrict__ counts,
                                                      int* __restrict__ ctr,
                                                      float* __restrict__ out) {
    __shared__ __align__(16) float lbins[8][104];
    __shared__ __align__(16) unsigned char ltab[4384];  // pad + 4225, 16B-gran copy
    __shared__ double ssum[256];
    __shared__ int scnt[256];
    __shared__ int lastFlag;
    int t = threadIdx.x;
    int m = t & 7, g = t >> 3;            // g: y-slot within group of 32
    int kz = blockIdx.x >> 2;
    int s0 = (blockIdx.x & 3) << 5;
    int f = blockIdx.y;
    int p = s0 + g;

    // issue all 16 A loads up front (wave covers 512B contiguous per instr)
    const float2* base = A + (size_t)f * FSTRIDE + (size_t)kz * 16384
                           + (size_t)(p >> 3) * 1024 + (p & 7);
    float2 r[16];
#pragma unroll
    for (int j = 0; j < 16; ++j) r[j] = base[8 * m + 64 * j];   // x = m+8j

    // vectorized staging (independent of r loads; one wait covers all)
    if (t < 208) ((float4*)lbins)[t] = make_float4(0.f, 0.f, 0.f, 0.f);
    int rowb = kz * 4225;
    int ab   = rowb & ~15;                 // aligned-down row start
    int pad  = rowb & 15;
    const uint4* osrc = (const uint4*)(oct + ab);
    ((uint4*)ltab)[t] = osrc[t];           // 256*16 = 4096 B
    if (t < 14) ((uint4*)ltab)[256 + t] = osrc[256 + t];  // -> 4320 >= pad+4225

    // pin all 16 float2 live -> batched load completion before FFT
    asm volatile("" : "+v"(r[0]), "+v"(r[1]), "+v"(r[2]), "+v"(r[3]),
                      "+v"(r[4]), "+v"(r[5]), "+v"(r[6]), "+v"(r[7]),
                      "+v"(r[8]), "+v"(r[9]), "+v"(r[10]), "+v"(r[11]),
                      "+v"(r[12]), "+v"(r[13]), "+v"(r[14]), "+v"(r[15]));
    fft128_r16(r, m);
    __syncthreads();                      // ltab + lbins ready

    const unsigned char* lt = ltab + pad;
    int ky = (br3(p & 7) << 4) | br4(p >> 3);
    int mky = (ky <= 64) ? ky : 128 - ky;
    int b3x = br3(m) << 4;
#pragma unroll
    for (int j = 0; j < 16; ++j) {
        int kx = b3x | br4(j);
        int mkx = (kx <= 64) ? kx : 128 - kx;
        float pk = r[j].x * r[j].x + r[j].y * r[j].y;
        atomicAdd(&lbins[t & 7][lt[mkx * 65 + mky]], pk);
    }
    __syncthreads();
    if (t < 101) {
        float wz = (kz == 0 || kz == 64) ? 1.0f : 2.0f;
        float v = lbins[0][t] + lbins[1][t] + lbins[2][t] + lbins[3][t] +
                  lbins[4][t] + lbins[5][t] + lbins[6][t] + lbins[7][t];
        if (v != 0.0f) atomicAdd(&sums[f * 101 + t], v * (NORMF) * wz);
    }

    // -------- fused finalize: last block computes the scalar loss --------
    __threadfence();
    if (t == 0) lastFlag = (atomicAdd(ctr, 1) == NBLK_XBIN - 1);
    __syncthreads();
    if (!lastFlag) return;

    double local = 0.0;
    int nloc = 0;
    if (t < KBINS) {
        int c = __hip_atomic_load(&counts[t], __ATOMIC_RELAXED, __HIP_MEMORY_SCOPE_AGENT);
        if (c > 0) {
            double start, step, stop;
            bin_params(&start, &step, &stop);
            double e0 = bin_edge(t, start, step, stop);
            double e1 = bin_edge(t + 1, start, step, stop);
            float kc  = (float)(0.5 * (e0 + e1));
            float kc3 = kc * kc * kc;
            const float two_pi2 = (float)(2.0 * M_PI * M_PI);
            float cf = (float)c;
            for (int b = 0; b < 8; ++b) {
                float sp = __hip_atomic_load(&sums[b * 101 + t], __ATOMIC_RELAXED,
                                             __HIP_MEMORY_SCOPE_AGENT);
                float st = __hip_atomic_load(&sums[(8 + b) * 101 + t], __ATOMIC_RELAXED,
                                             __HIP_MEMORY_SCOPE_AGENT);
                float pm_p = sp / cf;
                float pm_t = st / cf;
                float dsq_p = pm_p * kc3 / two_pi2;
                float dsq_t = pm_t * kc3 / two_pi2;
                float d = fabsf(log10f(dsq_t) - log10f(dsq_p));
                local += (double)d;
            }
            nloc = 8;
        }
    }
    ssum[t] = local;
    scnt[t] = nloc;
    __syncthreads();
    for (int off = 128; off > 0; off >>= 1) {
        if (t < off) { ssum[t] += ssum[t + off]; scnt[t] += scnt[t + off]; }
        __syncthreads();
    }
    if (t == 0) out[0] = (float)(ssum[0] / (double)scnt[0]);
}

// ---------------- launch ----------------
extern "C" void kernel_launch(void* const* d_in, const int* in_sizes, int n_in,
                              void* d_out, int out_size, void* d_ws, size_t ws_size,
                              hipStream_t stream) {
    (void)in_sizes; (void)n_in; (void)out_size; (void)ws_size;
    const float* pred   = (const float*)d_in[0];
    const float* target = (const float*)d_in[1];
    float* out = (float*)d_out;
    char* ws = (char*)d_ws;

    float* sums        = (float*)(ws + WS_SUMS_OFF);   // [16][101]
    int* counts        = (int*)(ws + WS_CNT_OFF);      // [101]
    int* ctr           = (int*)(ws + WS_CTR_OFF);      // [1]
    unsigned char* oct = (unsigned char*)(ws + WS_OCT_OFF);
    float2* A          = (float2*)(ws + WS_TRANS_OFF); // tiled layout per field

    hipMemsetAsync(ws, 0, 8192, stream);               // sums + counts + ctr

    // y==0: oct table (concurrent with zy); y>=1: zy planes for field y-1
    k_zy_oct<<<dim3(128, NFIELDS + 1), 512, 0, stream>>>(pred, target, A, oct, counts);
    k_fft_x_bin<<<dim3(65 * 4, NFIELDS), 256, 0, stream>>>(A, oct, sums, counts, ctr, out);
}

// Round 7
// 305.383 us; speedup vs baseline: 1.6766x; 1.6766x over previous
//
#include <hip/hip_runtime.h>
#include <math.h>

#ifndef M_PI
#define M_PI 3.14159265358979323846
#endif

// ---------------- constants ----------------
#define NSIDE 128
#define NVOX  2097152          // 128^3
#define KBINS 100
#define NFIELDS 16             // 8 pred + 8 target
#define NORMF (27.0f / 2097152.0f)   // LPIX^3 / N^3
#define FSTRIDE ((size_t)65 * 16384) // float2 elems per field

// A layout (float2 units), per field:
//   elem(kz, p, x) = kz*16384 + (p>>3)*1024 + x*8 + (p&7)
// p = y-slot (ky slot order), x = spatial x, kz = 0..64.

// ws layout (bytes)
#define WS_SUMS_OFF   0                       // float[16*101]
#define WS_CNT_OFF    6464                    // int[101]
#define WS_CTR_OFF    7936                    // int[1] (zeroed, unused now)
#define WS_OCT_OFF    8192                    // uint8[65*65*65], kz-major: oct[c][a][b]
#define WS_TRANS_OFF  282880                  // float2[16 * FSTRIDE] = 136.3 MB

// ---------------- exact numpy binning replication (fp64) ----------------
__device__ __forceinline__ double bin_edge(int i, double start, double step, double stop) {
    if (i == 100) return stop;
    return __dadd_rn(__dmul_rn((double)i, step), start);
}

__device__ __forceinline__ void bin_params(double* start, double* step, double* stop) {
    const double inv   = 1.0 / 384.0;
    const double twopi = 2.0 * M_PI;
    double k1 = __dmul_rn(twopi, __dmul_rn(1.0, inv));
    *start = sqrt(__dadd_rn(__dadd_rn(0.0, 0.0), __dmul_rn(k1, k1)));
    double k64 = __dmul_rn(twopi, __dmul_rn(-64.0, inv));
    double s64 = __dmul_rn(k64, k64);
    *stop = sqrt(__dadd_rn(__dadd_rn(s64, s64), s64));
    *step = (*stop - *start) / 100.0;
}

__device__ int compute_bin(int ix, int iy, int iz) {
    const double inv   = 1.0 / 384.0;
    const double twopi = 2.0 * M_PI;
    double fx = (double)(ix < 64 ? ix : ix - 128);
    double fy = (double)(iy < 64 ? iy : iy - 128);
    double fz = (double)(iz < 64 ? iz : iz - 128);
    double kx = __dmul_rn(twopi, __dmul_rn(fx, inv));
    double ky = __dmul_rn(twopi, __dmul_rn(fy, inv));
    double kz = __dmul_rn(twopi, __dmul_rn(fz, inv));
    double sq = __dadd_rn(__dadd_rn(__dmul_rn(kx, kx), __dmul_rn(ky, ky)), __dmul_rn(kz, kz));
    double kmag = sqrt(sq);
    if (!(kmag > 0.0)) return 100;                   // DC -> dropped bin
    double start, step, stop;
    bin_params(&start, &step, &stop);
    double t = (kmag - start) / step;
    int c = (int)floor(t);
    if (c < -1) c = -1;
    if (c > 100) c = 100;
    while (c < 100 && kmag >= bin_edge(c + 1, start, step, stop)) ++c;
    while (c >= 0 && kmag < bin_edge(c, start, step, stop)) --c;
    if (c < 0) c = 0;
    if (c > 99) c = 99;
    return c;
}

// ---------------- bit reversal helpers ----------------
__device__ __forceinline__ int br3(int v) { return ((v & 1) << 2) | (v & 2) | ((v >> 2) & 1); }
__device__ __forceinline__ int br4(int v) {
    return ((v & 1) << 3) | ((v & 2) << 1) | ((v & 4) >> 1) | ((v & 8) >> 3);
}

__device__ __forceinline__ float2 f2add(float2 a, float2 b) { return make_float2(a.x + b.x, a.y + b.y); }
__device__ __forceinline__ float2 f2sub(float2 a, float2 b) { return make_float2(a.x - b.x, a.y - b.y); }
__device__ __forceinline__ float2 cmul(float2 a, float2 w) {
    return make_float2(a.x * w.x - a.y * w.y, a.x * w.y + a.y * w.x);
}
__device__ __forceinline__ float2 twid(float r) {   // e^{2*pi*i*r}, r in revolutions
    return make_float2(__builtin_amdgcn_cosf(r), __builtin_amdgcn_sinf(r));
}

// ---------------- R=16 "slot" 128-pt FFT (lane m holds n = m + 8j) ----------------
// Output: position n = m+8j holds X[bitrev7(n)] -> k = (br3(m)<<4) | br4(j).
__device__ __forceinline__ void fft128_r16(float2 r[16], int m) {
    const float fm = (float)m;
#pragma unroll
    for (int j = 0; j < 8; ++j) {
        float2 W = twid(-(fm + 8.0f * (float)j) * (1.0f / 128.0f));
        float2 a = r[j], b = r[j + 8];
        r[j]     = f2add(a, b);
        r[j + 8] = cmul(f2sub(a, b), W);
    }
#pragma unroll
    for (int j = 0; j < 4; ++j) {
        float2 W = twid(-(fm + 8.0f * (float)j) * (1.0f / 64.0f));
#pragma unroll
        for (int half = 0; half < 16; half += 8) {
            float2 a = r[half + j], b = r[half + j + 4];
            r[half + j]     = f2add(a, b);
            r[half + j + 4] = cmul(f2sub(a, b), W);
        }
    }
#pragma unroll
    for (int j = 0; j < 2; ++j) {
        float2 W = twid(-(fm + 8.0f * (float)j) * (1.0f / 32.0f));
#pragma unroll
        for (int q = 0; q < 16; q += 4) {
            float2 a = r[q + j], b = r[q + j + 2];
            r[q + j]     = f2add(a, b);
            r[q + j + 2] = cmul(f2sub(a, b), W);
        }
    }
    {
        float2 W = twid(-fm * (1.0f / 16.0f));
#pragma unroll
        for (int q = 0; q < 16; q += 2) {
            float2 a = r[q], b = r[q + 1];
            r[q]     = f2add(a, b);
            r[q + 1] = cmul(f2sub(a, b), W);
        }
    }
#pragma unroll
    for (int h = 4; h >= 2; h >>= 1) {
        bool hi = (m & h) != 0;
        float2 W = twid(-(float)(m & (h - 1)) / (float)(2 * h));
#pragma unroll
        for (int j = 0; j < 16; ++j) {
            float2 x = r[j];
            float2 v = make_float2(__shfl_xor(x.x, h, 64), __shfl_xor(x.y, h, 64));
            float2 s = f2add(x, v);
            float2 d = cmul(f2sub(v, x), W);
            r[j] = hi ? d : s;
        }
    }
    {
        bool hi = (m & 1) != 0;
#pragma unroll
        for (int j = 0; j < 16; ++j) {
            float2 x = r[j];
            float2 v = make_float2(__shfl_xor(x.x, 1, 64), __shfl_xor(x.y, 1, 64));
            r[j] = hi ? f2sub(v, x) : f2add(x, v);
        }
    }
}

// ---------------- "contiguous" 128-pt FFT (lane m holds n = 16m + j) ----------------
// Output: position (m,j) holds X[8*br4(j) + br3(m)]. Zero sin/cos.
__device__ __forceinline__ void fft128_c16(float2 r[16], int m) {
    const float S2 = 0.70710678118654752f;
    // ---- h=64: partner m^4; W = Wm[m&3] * e^{-2pi i j/128}
    {
        int q = m & 3;
        float2 Wm = make_float2(q == 0 ? 1.f : (q == 1 ? S2 : (q == 2 ? 0.f : -S2)),
                                q == 0 ? 0.f : (q == 2 ? -1.f : -S2));
        bool hi = (m & 4) != 0;
        const float2 C[16] = {
            {1.f,0.f},{0.99879546f,-0.04906767f},{0.99518473f,-0.09801714f},
            {0.98917651f,-0.14673047f},{0.98078528f,-0.19509032f},{0.97003125f,-0.24298018f},
            {0.95694034f,-0.29028468f},{0.94154407f,-0.33688985f},{0.92387953f,-0.38268343f},
            {0.90398929f,-0.42755509f},{0.88192126f,-0.47139674f},{0.85772861f,-0.51410274f},
            {0.83146961f,-0.55557023f},{0.80320753f,-0.59569930f},{0.77301045f,-0.63439328f},
            {0.74095113f,-0.67155895f} };
#pragma unroll
        for (int j = 0; j < 16; ++j) {
            float2 x = r[j];
            float2 v = make_float2(__shfl_xor(x.x, 4, 64), __shfl_xor(x.y, 4, 64));
            float2 s = f2add(x, v);
            float2 d = cmul(cmul(f2sub(v, x), Wm), C[j]);
            r[j] = hi ? d : s;
        }
    }
    // ---- h=32: partner m^2; W = (m&1 ? -i : 1) * e^{-2pi i j/64}
    {
        bool w = (m & 1) != 0;
        bool hi = (m & 2) != 0;
        const float2 C[16] = {
            {1.f,0.f},{0.99518473f,-0.09801714f},{0.98078528f,-0.19509032f},
            {0.95694034f,-0.29028468f},{0.92387953f,-0.38268343f},{0.88192126f,-0.47139674f},
            {0.83146961f,-0.55557023f},{0.77301045f,-0.63439328f},{S2,-S2},
            {0.63439328f,-0.77301045f},{0.55557023f,-0.83146961f},{0.47139674f,-0.88192126f},
            {0.38268343f,-0.92387953f},{0.29028468f,-0.95694034f},{0.19509032f,-0.98078528f},
            {0.09801714f,-0.99518473f} };
#pragma unroll
        for (int j = 0; j < 16; ++j) {
            float2 x = r[j];
            float2 v = make_float2(__shfl_xor(x.x, 2, 64), __shfl_xor(x.y, 2, 64));
            float2 s = f2add(x, v);
            float2 d = f2sub(v, x);
            d = w ? make_float2(d.y, -d.x) : d;
            d = cmul(d, C[j]);
            r[j] = hi ? d : s;
        }
    }
    // ---- h=16: partner m^1; W = e^{-2pi i j/32}
    {
        bool hi = (m & 1) != 0;
        const float2 C[16] = {
            {1.f,0.f},{0.98078528f,-0.19509032f},{0.92387953f,-0.38268343f},
            {0.83146961f,-0.55557023f},{S2,-S2},{0.55557023f,-0.83146961f},
            {0.38268343f,-0.92387953f},{0.19509032f,-0.98078528f},{0.f,-1.f},
            {-0.19509032f,-0.98078528f},{-0.38268343f,-0.92387953f},{-0.55557023f,-0.83146961f},
            {-S2,-S2},{-0.83146961f,-0.55557023f},{-0.92387953f,-0.38268343f},
            {-0.98078528f,-0.19509032f} };
#pragma unroll
        for (int j = 0; j < 16; ++j) {
            float2 x = r[j];
            float2 v = make_float2(__shfl_xor(x.x, 1, 64), __shfl_xor(x.y, 1, 64));
            float2 s = f2add(x, v);
            float2 d = cmul(f2sub(v, x), C[j]);
            r[j] = hi ? d : s;
        }
    }
    // ---- h=8
    {
        const float2 C[8] = {
            {1.f,0.f},{0.92387953f,-0.38268343f},{S2,-S2},{0.38268343f,-0.92387953f},
            {0.f,-1.f},{-0.38268343f,-0.92387953f},{-S2,-S2},{-0.92387953f,-0.38268343f} };
#pragma unroll
        for (int j = 0; j < 8; ++j) {
            float2 a = r[j], b = r[j + 8];
            r[j]     = f2add(a, b);
            r[j + 8] = cmul(f2sub(a, b), C[j]);
        }
    }
    // ---- h=4
    {
        const float2 C[4] = { {1.f,0.f},{S2,-S2},{0.f,-1.f},{-S2,-S2} };
#pragma unroll
        for (int q = 0; q < 16; q += 8)
#pragma unroll
            for (int j = 0; j < 4; ++j) {
                float2 a = r[q + j], b = r[q + j + 4];
                r[q + j]     = f2add(a, b);
                r[q + j + 4] = cmul(f2sub(a, b), C[j]);
            }
    }
    // ---- h=2
    {
#pragma unroll
        for (int q = 0; q < 16; q += 4) {
            { float2 a = r[q], b = r[q + 2]; r[q] = f2add(a, b); r[q + 2] = f2sub(a, b); }
            { float2 a = r[q + 1], b = r[q + 3]; float2 d = f2sub(a, b);
              r[q + 1] = f2add(a, b); r[q + 3] = make_float2(d.y, -d.x); }
        }
    }
    // ---- h=1
    {
#pragma unroll
        for (int q = 0; q < 16; q += 2) {
            float2 a = r[q], b = r[q + 1];
            r[q] = f2add(a, b); r[q + 1] = f2sub(a, b);
        }
    }
}

// ---------------- fused Z+Y (y>=1) and oct-table (y==0) kernel ----------------
// y==0: oct table + weighted mode counts (concurrent with zy planes; no fences).
// y>=1: R3's verified zy body, verbatim (512 thr, 2-iter phases).
__global__ __launch_bounds__(512, 4) void k_zy_oct(const float* __restrict__ pred,
                                                   const float* __restrict__ target,
                                                   float2* __restrict__ A,
                                                   unsigned char* __restrict__ oct,
                                                   int* __restrict__ counts) {
    __shared__ float2 lds[65][132];
    int t = threadIdx.x;

    if (blockIdx.y == 0) {
        // -------- oct path --------
        int* lcnt = (int*)&lds[0][0];            // 4*104 ints, aliased into lds
        for (int j = t; j < 4 * 104; j += 512) lcnt[j] = 0;
        __syncthreads();
        for (int idx = blockIdx.x * 512 + t; idx < 65 * 65 * 65; idx += 128 * 512) {
            int c = idx % 65;
            int r = idx / 65;
            int b = r % 65;
            int a = r / 65;
            int id = compute_bin(a, b, c);
            oct[c * 4225 + a * 65 + b] = (unsigned char)id;
            if (id < 100) {
                int w = ((a == 0 || a == 64) ? 1 : 2) *
                        ((b == 0 || b == 64) ? 1 : 2) *
                        ((c == 0 || c == 64) ? 1 : 2);
                atomicAdd(&lcnt[(t & 3) * 104 + id], w);
            }
        }
        __syncthreads();
        if (t < 101) {
            int tot = lcnt[t] + lcnt[104 + t] + lcnt[208 + t] + lcnt[312 + t];
            if (tot) atomicAdd(&counts[t], tot);
        }
        return;
    }

    // -------- zy path (R3 verbatim) --------
    int m = t & 7, row = t >> 3;          // 64 groups
    int x = blockIdx.x;
    int f = blockIdx.y - 1;
    const float* in = (f < 8) ? (pred + (size_t)f * NVOX)
                              : (target + (size_t)(f - 8) * NVOX);

    // Phase 1: z-FFTs (contiguous-lane variant), decimate kz<=64
    int b3 = br3(m);
#pragma unroll
    for (int y0 = 0; y0 < 128; y0 += 64) {
        int y = y0 + row;
        const float4* s4 = reinterpret_cast<const float4*>(
            in + (size_t)x * 16384 + (size_t)y * 128 + 16 * m);
        float2 r[16];
#pragma unroll
        for (int q = 0; q < 4; ++q) {
            float4 v = s4[q];
            r[4 * q + 0] = make_float2(v.x, 0.f);
            r[4 * q + 1] = make_float2(v.y, 0.f);
            r[4 * q + 2] = make_float2(v.z, 0.f);
            r[4 * q + 3] = make_float2(v.w, 0.f);
        }
        fft128_c16(r, m);
        // kz(m,j) = 8*br4(j) + br3(m); kz<=64 <=> j even, plus (m=0,j=1)->kz=64
#pragma unroll
        for (int j = 0; j < 16; j += 2) {
            int kz = 8 * br4(j) + b3;
            lds[kz][y] = r[j];
        }
        if (m == 0) lds[64][y] = r[1];
    }
    __syncthreads();                      // LDS plane [65][128] complete

    // Phase 2: y-FFTs from LDS, write A (tiled layout)
    float2* basef = A + (size_t)f * FSTRIDE + (size_t)x * 8;
#pragma unroll
    for (int k0 = 0; k0 < 128; k0 += 64) {
        int kz = k0 + row;
        if (kz <= 64) {
            float2 r[16];
#pragma unroll
            for (int j = 0; j < 16; ++j) r[j] = lds[kz][m + 8 * j];
            fft128_r16(r, m);
            float2* dst = basef + (size_t)kz * 16384;
            // slot p = m+8j -> offset (p>>3)*1024 + (p&7) = j*1024 + m
#pragma unroll
            for (int j = 0; j < 16; ++j) dst[j * 1024 + m] = r[j];
        }
    }
}

// ---------------- Pass X (R3 verbatim, no epilogue) ----------------
__global__ __launch_bounds__(256, 6) void k_fft_x_bin(const float2* __restrict__ A,
                                                      const unsigned char* __restrict__ oct,
                                                      float* __restrict__ sums) {
    __shared__ __align__(16) float lbins[8][104];
    __shared__ __align__(16) unsigned char ltab[4384];  // pad + 4225, 16B-gran copy
    int t = threadIdx.x;
    int m = t & 7, g = t >> 3;            // g: y-slot within group of 32
    int kz = blockIdx.x >> 2;
    int s0 = (blockIdx.x & 3) << 5;
    int f = blockIdx.y;
    int p = s0 + g;

    // issue all 16 A loads up front (wave covers 512B contiguous per instr)
    const float2* base = A + (size_t)f * FSTRIDE + (size_t)kz * 16384
                           + (size_t)(p >> 3) * 1024 + (p & 7);
    float2 r[16];
#pragma unroll
    for (int j = 0; j < 16; ++j) r[j] = base[8 * m + 64 * j];   // x = m+8j

    // vectorized staging (independent of r loads; one wait covers all)
    if (t < 208) ((float4*)lbins)[t] = make_float4(0.f, 0.f, 0.f, 0.f);
    int rowb = kz * 4225;
    int ab   = rowb & ~15;                 // aligned-down row start
    int pad  = rowb & 15;
    const uint4* osrc = (const uint4*)(oct + ab);
    ((uint4*)ltab)[t] = osrc[t];           // 256*16 = 4096 B
    if (t < 14) ((uint4*)ltab)[256 + t] = osrc[256 + t];  // -> 4320 >= pad+4225

    // pin all 16 float2 live -> batched load completion before FFT
    asm volatile("" : "+v"(r[0]), "+v"(r[1]), "+v"(r[2]), "+v"(r[3]),
                      "+v"(r[4]), "+v"(r[5]), "+v"(r[6]), "+v"(r[7]),
                      "+v"(r[8]), "+v"(r[9]), "+v"(r[10]), "+v"(r[11]),
                      "+v"(r[12]), "+v"(r[13]), "+v"(r[14]), "+v"(r[15]));
    fft128_r16(r, m);
    __syncthreads();                      // ltab + lbins ready

    const unsigned char* lt = ltab + pad;
    int ky = (br3(p & 7) << 4) | br4(p >> 3);
    int mky = (ky <= 64) ? ky : 128 - ky;
    int b3x = br3(m) << 4;
#pragma unroll
    for (int j = 0; j < 16; ++j) {
        int kx = b3x | br4(j);
        int mkx = (kx <= 64) ? kx : 128 - kx;
        float pk = r[j].x * r[j].x + r[j].y * r[j].y;
        atomicAdd(&lbins[t & 7][lt[mkx * 65 + mky]], pk);
    }
    __syncthreads();
    if (t < 101) {
        float wz = (kz == 0 || kz == 64) ? 1.0f : 2.0f;
        float v = lbins[0][t] + lbins[1][t] + lbins[2][t] + lbins[3][t] +
                  lbins[4][t] + lbins[5][t] + lbins[6][t] + lbins[7][t];
        if (v != 0.0f) atomicAdd(&sums[f * 101 + t], v * (NORMF) * wz);
    }
}

// ---------------- Finalize: separate tiny kernel (NO per-block device fences) ------
__global__ __launch_bounds__(128) void k_finalize(const float* __restrict__ sums,
                                                  const int* __restrict__ counts,
                                                  float* __restrict__ out) {
    __shared__ double ssum[128];
    __shared__ int scnt[128];
    int k = threadIdx.x;
    double local = 0.0;
    int nloc = 0;
    if (k < KBINS) {
        int c = counts[k];
        if (c > 0) {
            double start, step, stop;
            bin_params(&start, &step, &stop);
            double e0 = bin_edge(k, start, step, stop);
            double e1 = bin_edge(k + 1, start, step, stop);
            float kc  = (float)(0.5 * (e0 + e1));
            float kc3 = kc * kc * kc;
            const float two_pi2 = (float)(2.0 * M_PI * M_PI);
            float cf = (float)c;
            for (int b = 0; b < 8; ++b) {
                float pm_p = sums[b * 101 + k] / cf;
                float pm_t = sums[(8 + b) * 101 + k] / cf;
                float dsq_p = pm_p * kc3 / two_pi2;
                float dsq_t = pm_t * kc3 / two_pi2;
                float d = fabsf(log10f(dsq_t) - log10f(dsq_p));
                local += (double)d;
            }
            nloc = 8;
        }
    }
    ssum[k] = local;
    scnt[k] = nloc;
    __syncthreads();
    for (int off = 64; off > 0; off >>= 1) {
        if (k < off) { ssum[k] += ssum[k + off]; scnt[k] += scnt[k + off]; }
        __syncthreads();
    }
    if (k == 0) out[0] = (float)(ssum[0] / (double)scnt[0]);
}

// ---------------- launch ----------------
extern "C" void kernel_launch(void* const* d_in, const int* in_sizes, int n_in,
                              void* d_out, int out_size, void* d_ws, size_t ws_size,
                              hipStream_t stream) {
    (void)in_sizes; (void)n_in; (void)out_size; (void)ws_size;
    const float* pred   = (const float*)d_in[0];
    const float* target = (const float*)d_in[1];
    float* out = (float*)d_out;
    char* ws = (char*)d_ws;

    float* sums        = (float*)(ws + WS_SUMS_OFF);   // [16][101]
    int* counts        = (int*)(ws + WS_CNT_OFF);      // [101]
    unsigned char* oct = (unsigned char*)(ws + WS_OCT_OFF);
    float2* A          = (float2*)(ws + WS_TRANS_OFF); // tiled layout per field

    hipMemsetAsync(ws, 0, 8192, stream);               // sums + counts (+ctr slot)

    // y==0: oct table (concurrent with zy); y>=1: zy planes for field y-1
    k_zy_oct<<<dim3(128, NFIELDS + 1), 512, 0, stream>>>(pred, target, A, oct, counts);
    k_fft_x_bin<<<dim3(65 * 4, NFIELDS), 256, 0, stream>>>(A, oct, sums);
    k_finalize<<<1, 128, 0, stream>>>(sums, counts, out);
}

// Round 8
// 305.339 us; speedup vs baseline: 1.6768x; 1.0001x over previous
//
#include <hip/hip_runtime.h>
#include <math.h>

#ifndef M_PI
#define M_PI 3.14159265358979323846
#endif

// ---------------- constants ----------------
#define NSIDE 128
#define NVOX  2097152          // 128^3
#define KBINS 100
#define NFIELDS 16             // 8 pred + 8 target
#define NORMF (27.0f / 2097152.0f)   // LPIX^3 / N^3
#define FSTRIDE ((size_t)65 * 16384) // float2 elems per field

// A layout (float2 units), per field:
//   elem(kz, p, x) = kz*16384 + (p>>3)*1024 + x*8 + (p&7)
// p = y-slot (ky slot order), x = spatial x, kz = 0..64.

// ws layout (bytes)
#define WS_SUMS_OFF   0                       // float[16*101]
#define WS_CNT_OFF    6464                    // int[101]
#define WS_CTR_OFF    7936                    // int[1] (zeroed, unused)
#define WS_OCT_OFF    8192                    // uint8[65*65*65], kz-major: oct[c][a][b]
#define WS_TRANS_OFF  282880                  // float2[16 * FSTRIDE] = 136.3 MB

// ---------------- exact numpy binning replication (fp64) ----------------
__device__ __forceinline__ double bin_edge(int i, double start, double step, double stop) {
    if (i == 100) return stop;
    return __dadd_rn(__dmul_rn((double)i, step), start);
}

__device__ __forceinline__ void bin_params(double* start, double* step, double* stop) {
    const double inv   = 1.0 / 384.0;
    const double twopi = 2.0 * M_PI;
    double k1 = __dmul_rn(twopi, __dmul_rn(1.0, inv));
    *start = sqrt(__dadd_rn(__dadd_rn(0.0, 0.0), __dmul_rn(k1, k1)));
    double k64 = __dmul_rn(twopi, __dmul_rn(-64.0, inv));
    double s64 = __dmul_rn(k64, k64);
    *stop = sqrt(__dadd_rn(__dadd_rn(s64, s64), s64));
    *step = (*stop - *start) / 100.0;
}

__device__ int compute_bin(int ix, int iy, int iz) {
    const double inv   = 1.0 / 384.0;
    const double twopi = 2.0 * M_PI;
    double fx = (double)(ix < 64 ? ix : ix - 128);
    double fy = (double)(iy < 64 ? iy : iy - 128);
    double fz = (double)(iz < 64 ? iz : iz - 128);
    double kx = __dmul_rn(twopi, __dmul_rn(fx, inv));
    double ky = __dmul_rn(twopi, __dmul_rn(fy, inv));
    double kz = __dmul_rn(twopi, __dmul_rn(fz, inv));
    double sq = __dadd_rn(__dadd_rn(__dmul_rn(kx, kx), __dmul_rn(ky, ky)), __dmul_rn(kz, kz));
    double kmag = sqrt(sq);
    if (!(kmag > 0.0)) return 100;                   // DC -> dropped bin
    double start, step, stop;
    bin_params(&start, &step, &stop);
    double t = (kmag - start) / step;
    int c = (int)floor(t);
    if (c < -1) c = -1;
    if (c > 100) c = 100;
    while (c < 100 && kmag >= bin_edge(c + 1, start, step, stop)) ++c;
    while (c >= 0 && kmag < bin_edge(c, start, step, stop)) --c;
    if (c < 0) c = 0;
    if (c > 99) c = 99;
    return c;
}

// ---------------- bit reversal helpers ----------------
__device__ __forceinline__ int br3(int v) { return ((v & 1) << 2) | (v & 2) | ((v >> 2) & 1); }
__device__ __forceinline__ int br4(int v) {
    return ((v & 1) << 3) | ((v & 2) << 1) | ((v & 4) >> 1) | ((v & 8) >> 3);
}

__device__ __forceinline__ float2 f2add(float2 a, float2 b) { return make_float2(a.x + b.x, a.y + b.y); }
__device__ __forceinline__ float2 f2sub(float2 a, float2 b) { return make_float2(a.x - b.x, a.y - b.y); }
__device__ __forceinline__ float2 cmul(float2 a, float2 w) {
    return make_float2(a.x * w.x - a.y * w.y, a.x * w.y + a.y * w.x);
}
__device__ __forceinline__ float2 twid(float r) {   // e^{2*pi*i*r}, r in revolutions
    return make_float2(__builtin_amdgcn_cosf(r), __builtin_amdgcn_sinf(r));
}

// ---------------- R=16 "slot" 128-pt FFT (lane m holds n = m + 8j) ----------------
// Output: position n = m+8j holds X[bitrev7(n)] -> k = (br3(m)<<4) | br4(j).
__device__ __forceinline__ void fft128_r16(float2 r[16], int m) {
    const float fm = (float)m;
#pragma unroll
    for (int j = 0; j < 8; ++j) {
        float2 W = twid(-(fm + 8.0f * (float)j) * (1.0f / 128.0f));
        float2 a = r[j], b = r[j + 8];
        r[j]     = f2add(a, b);
        r[j + 8] = cmul(f2sub(a, b), W);
    }
#pragma unroll
    for (int j = 0; j < 4; ++j) {
        float2 W = twid(-(fm + 8.0f * (float)j) * (1.0f / 64.0f));
#pragma unroll
        for (int half = 0; half < 16; half += 8) {
            float2 a = r[half + j], b = r[half + j + 4];
            r[half + j]     = f2add(a, b);
            r[half + j + 4] = cmul(f2sub(a, b), W);
        }
    }
#pragma unroll
    for (int j = 0; j < 2; ++j) {
        float2 W = twid(-(fm + 8.0f * (float)j) * (1.0f / 32.0f));
#pragma unroll
        for (int q = 0; q < 16; q += 4) {
            float2 a = r[q + j], b = r[q + j + 2];
            r[q + j]     = f2add(a, b);
            r[q + j + 2] = cmul(f2sub(a, b), W);
        }
    }
    {
        float2 W = twid(-fm * (1.0f / 16.0f));
#pragma unroll
        for (int q = 0; q < 16; q += 2) {
            float2 a = r[q], b = r[q + 1];
            r[q]     = f2add(a, b);
            r[q + 1] = cmul(f2sub(a, b), W);
        }
    }
#pragma unroll
    for (int h = 4; h >= 2; h >>= 1) {
        bool hi = (m & h) != 0;
        float2 W = twid(-(float)(m & (h - 1)) / (float)(2 * h));
#pragma unroll
        for (int j = 0; j < 16; ++j) {
            float2 x = r[j];
            float2 v = make_float2(__shfl_xor(x.x, h, 64), __shfl_xor(x.y, h, 64));
            float2 s = f2add(x, v);
            float2 d = cmul(f2sub(v, x), W);
            r[j] = hi ? d : s;
        }
    }
    {
        bool hi = (m & 1) != 0;
#pragma unroll
        for (int j = 0; j < 16; ++j) {
            float2 x = r[j];
            float2 v = make_float2(__shfl_xor(x.x, 1, 64), __shfl_xor(x.y, 1, 64));
            r[j] = hi ? f2sub(v, x) : f2add(x, v);
        }
    }
}

// ---------------- "contiguous" 128-pt FFT (lane m holds n = 16m + j) ----------------
// Output: position (m,j) holds X[8*br4(j) + br3(m)]. Zero sin/cos.
__device__ __forceinline__ void fft128_c16(float2 r[16], int m) {
    const float S2 = 0.70710678118654752f;
    // ---- h=64: partner m^4; W = Wm[m&3] * e^{-2pi i j/128}
    {
        int q = m & 3;
        float2 Wm = make_float2(q == 0 ? 1.f : (q == 1 ? S2 : (q == 2 ? 0.f : -S2)),
                                q == 0 ? 0.f : (q == 2 ? -1.f : -S2));
        bool hi = (m & 4) != 0;
        const float2 C[16] = {
            {1.f,0.f},{0.99879546f,-0.04906767f},{0.99518473f,-0.09801714f},
            {0.98917651f,-0.14673047f},{0.98078528f,-0.19509032f},{0.97003125f,-0.24298018f},
            {0.95694034f,-0.29028468f},{0.94154407f,-0.33688985f},{0.92387953f,-0.38268343f},
            {0.90398929f,-0.42755509f},{0.88192126f,-0.47139674f},{0.85772861f,-0.51410274f},
            {0.83146961f,-0.55557023f},{0.80320753f,-0.59569930f},{0.77301045f,-0.63439328f},
            {0.74095113f,-0.67155895f} };
#pragma unroll
        for (int j = 0; j < 16; ++j) {
            float2 x = r[j];
            float2 v = make_float2(__shfl_xor(x.x, 4, 64), __shfl_xor(x.y, 4, 64));
            float2 s = f2add(x, v);
            float2 d = cmul(cmul(f2sub(v, x), Wm), C[j]);
            r[j] = hi ? d : s;
        }
    }
    // ---- h=32: partner m^2; W = (m&1 ? -i : 1) * e^{-2pi i j/64}
    {
        bool w = (m & 1) != 0;
        bool hi = (m & 2) != 0;
        const float2 C[16] = {
            {1.f,0.f},{0.99518473f,-0.09801714f},{0.98078528f,-0.19509032f},
            {0.95694034f,-0.29028468f},{0.92387953f,-0.38268343f},{0.88192126f,-0.47139674f},
            {0.83146961f,-0.55557023f},{0.77301045f,-0.63439328f},{S2,-S2},
            {0.63439328f,-0.77301045f},{0.55557023f,-0.83146961f},{0.47139674f,-0.88192126f},
            {0.38268343f,-0.92387953f},{0.29028468f,-0.95694034f},{0.19509032f,-0.98078528f},
            {0.09801714f,-0.99518473f} };
#pragma unroll
        for (int j = 0; j < 16; ++j) {
            float2 x = r[j];
            float2 v = make_float2(__shfl_xor(x.x, 2, 64), __shfl_xor(x.y, 2, 64));
            float2 s = f2add(x, v);
            float2 d = f2sub(v, x);
            d = w ? make_float2(d.y, -d.x) : d;
            d = cmul(d, C[j]);
            r[j] = hi ? d : s;
        }
    }
    // ---- h=16: partner m^1; W = e^{-2pi i j/32}
    {
        bool hi = (m & 1) != 0;
        const float2 C[16] = {
            {1.f,0.f},{0.98078528f,-0.19509032f},{0.92387953f,-0.38268343f},
            {0.83146961f,-0.55557023f},{S2,-S2},{0.55557023f,-0.83146961f},
            {0.38268343f,-0.92387953f},{0.19509032f,-0.98078528f},{0.f,-1.f},
            {-0.19509032f,-0.98078528f},{-0.38268343f,-0.92387953f},{-0.55557023f,-0.83146961f},
            {-S2,-S2},{-0.83146961f,-0.55557023f},{-0.92387953f,-0.38268343f},
            {-0.98078528f,-0.19509032f} };
#pragma unroll
        for (int j = 0; j < 16; ++j) {
            float2 x = r[j];
            float2 v = make_float2(__shfl_xor(x.x, 1, 64), __shfl_xor(x.y, 1, 64));
            float2 s = f2add(x, v);
            float2 d = cmul(f2sub(v, x), C[j]);
            r[j] = hi ? d : s;
        }
    }
    // ---- h=8
    {
        const float2 C[8] = {
            {1.f,0.f},{0.92387953f,-0.38268343f},{S2,-S2},{0.38268343f,-0.92387953f},
            {0.f,-1.f},{-0.38268343f,-0.92387953f},{-S2,-S2},{-0.92387953f,-0.38268343f} };
#pragma unroll
        for (int j = 0; j < 8; ++j) {
            float2 a = r[j], b = r[j + 8];
            r[j]     = f2add(a, b);
            r[j + 8] = cmul(f2sub(a, b), C[j]);
        }
    }
    // ---- h=4
    {
        const float2 C[4] = { {1.f,0.f},{S2,-S2},{0.f,-1.f},{-S2,-S2} };
#pragma unroll
        for (int q = 0; q < 16; q += 8)
#pragma unroll
            for (int j = 0; j < 4; ++j) {
                float2 a = r[q + j], b = r[q + j + 4];
                r[q + j]     = f2add(a, b);
                r[q + j + 4] = cmul(f2sub(a, b), C[j]);
            }
    }
    // ---- h=2
    {
#pragma unroll
        for (int q = 0; q < 16; q += 4) {
            { float2 a = r[q], b = r[q + 2]; r[q] = f2add(a, b); r[q + 2] = f2sub(a, b); }
            { float2 a = r[q + 1], b = r[q + 3]; float2 d = f2sub(a, b);
              r[q + 1] = f2add(a, b); r[q + 3] = make_float2(d.y, -d.x); }
        }
    }
    // ---- h=1
    {
#pragma unroll
        for (int q = 0; q < 16; q += 2) {
            float2 a = r[q], b = r[q + 1];
            r[q] = f2add(a, b); r[q + 1] = f2sub(a, b);
        }
    }
}

// ---------------- fused Z+Y (y>=1) and oct-table (y==0) kernel ----------------
// y==0: oct table + weighted mode counts (concurrent with zy planes; no fences).
// y>=1: verified zy body (512 thr, 2-iter phases).
__global__ __launch_bounds__(512, 4) void k_zy_oct(const float* __restrict__ pred,
                                                   const float* __restrict__ target,
                                                   float2* __restrict__ A,
                                                   unsigned char* __restrict__ oct,
                                                   int* __restrict__ counts) {
    __shared__ float2 lds[65][132];
    int t = threadIdx.x;

    if (blockIdx.y == 0) {
        // -------- oct path --------
        int* lcnt = (int*)&lds[0][0];            // 4*104 ints, aliased into lds
        for (int j = t; j < 4 * 104; j += 512) lcnt[j] = 0;
        __syncthreads();
        for (int idx = blockIdx.x * 512 + t; idx < 65 * 65 * 65; idx += 128 * 512) {
            int c = idx % 65;
            int r = idx / 65;
            int b = r % 65;
            int a = r / 65;
            int id = compute_bin(a, b, c);
            oct[c * 4225 + a * 65 + b] = (unsigned char)id;
            if (id < 100) {
                int w = ((a == 0 || a == 64) ? 1 : 2) *
                        ((b == 0 || b == 64) ? 1 : 2) *
                        ((c == 0 || c == 64) ? 1 : 2);
                atomicAdd(&lcnt[(t & 3) * 104 + id], w);
            }
        }
        __syncthreads();
        if (t < 101) {
            int tot = lcnt[t] + lcnt[104 + t] + lcnt[208 + t] + lcnt[312 + t];
            if (tot) atomicAdd(&counts[t], tot);
        }
        return;
    }

    // -------- zy path --------
    int m = t & 7, row = t >> 3;          // 64 groups
    int x = blockIdx.x;
    int f = blockIdx.y - 1;
    const float* in = (f < 8) ? (pred + (size_t)f * NVOX)
                              : (target + (size_t)(f - 8) * NVOX);

    // Phase 1: z-FFTs (contiguous-lane variant), decimate kz<=64
    int b3 = br3(m);
#pragma unroll
    for (int y0 = 0; y0 < 128; y0 += 64) {
        int y = y0 + row;
        const float4* s4 = reinterpret_cast<const float4*>(
            in + (size_t)x * 16384 + (size_t)y * 128 + 16 * m);
        float2 r[16];
#pragma unroll
        for (int q = 0; q < 4; ++q) {
            float4 v = s4[q];
            r[4 * q + 0] = make_float2(v.x, 0.f);
            r[4 * q + 1] = make_float2(v.y, 0.f);
            r[4 * q + 2] = make_float2(v.z, 0.f);
            r[4 * q + 3] = make_float2(v.w, 0.f);
        }
        fft128_c16(r, m);
        // kz(m,j) = 8*br4(j) + br3(m); kz<=64 <=> j even, plus (m=0,j=1)->kz=64
#pragma unroll
        for (int j = 0; j < 16; j += 2) {
            int kz = 8 * br4(j) + b3;
            lds[kz][y] = r[j];
        }
        if (m == 0) lds[64][y] = r[1];
    }
    __syncthreads();                      // LDS plane [65][128] complete

    // Phase 2: y-FFTs from LDS, write A (tiled layout)
    float2* basef = A + (size_t)f * FSTRIDE + (size_t)x * 8;
#pragma unroll
    for (int k0 = 0; k0 < 128; k0 += 64) {
        int kz = k0 + row;
        if (kz <= 64) {
            float2 r[16];
#pragma unroll
            for (int j = 0; j < 16; ++j) r[j] = lds[kz][m + 8 * j];
            fft128_r16(r, m);
            float2* dst = basef + (size_t)kz * 16384;
            // slot p = m+8j -> offset (p>>3)*1024 + (p&7) = j*1024 + m
#pragma unroll
            for (int j = 0; j < 16; ++j) dst[j * 1024 + m] = r[j];
        }
    }
}

// ---------------- Pass X: c16 FFT (ZERO sincos) + power + binning ----------------
// Lane m holds x = 16m+j (contiguous-lane variant). Per load instr the wave
// covers 8x 64B segments (same class as zy's writes; R2 proved x_bin timing
// is insensitive to the A load pattern). Output decode: kx = 8*br4(j)+br3(m).
__global__ __launch_bounds__(256, 6) void k_fft_x_bin(const float2* __restrict__ A,
                                                      const unsigned char* __restrict__ oct,
                                                      float* __restrict__ sums) {
    __shared__ __align__(16) float lbins[8][104];
    __shared__ __align__(16) unsigned char ltab[4384];  // pad + 4225, 16B-gran copy
    int t = threadIdx.x;
    int m = t & 7, g = t >> 3;            // g: y-slot within group of 32
    int kz = blockIdx.x >> 2;
    int s0 = (blockIdx.x & 3) << 5;
    int f = blockIdx.y;
    int p = s0 + g;

    // issue all 16 A loads up front; lane m reads x = 16m+j
    const float2* base = A + (size_t)f * FSTRIDE + (size_t)kz * 16384
                           + (size_t)(p >> 3) * 1024 + (p & 7);
    float2 r[16];
#pragma unroll
    for (int j = 0; j < 16; ++j) r[j] = base[(size_t)(16 * m + j) * 8];

    // vectorized staging (independent of r loads; one wait covers all)
    if (t < 208) ((float4*)lbins)[t] = make_float4(0.f, 0.f, 0.f, 0.f);
    int rowb = kz * 4225;
    int ab   = rowb & ~15;                 // aligned-down row start
    int pad  = rowb & 15;
    const uint4* osrc = (const uint4*)(oct + ab);
    ((uint4*)ltab)[t] = osrc[t];           // 256*16 = 4096 B
    if (t < 14) ((uint4*)ltab)[256 + t] = osrc[256 + t];  // -> 4320 >= pad+4225

    // pin all 16 float2 live -> batched load completion before FFT
    asm volatile("" : "+v"(r[0]), "+v"(r[1]), "+v"(r[2]), "+v"(r[3]),
                      "+v"(r[4]), "+v"(r[5]), "+v"(r[6]), "+v"(r[7]),
                      "+v"(r[8]), "+v"(r[9]), "+v"(r[10]), "+v"(r[11]),
                      "+v"(r[12]), "+v"(r[13]), "+v"(r[14]), "+v"(r[15]));
    fft128_c16(r, m);                     // zero sin/cos, constant twiddles
    __syncthreads();                      // ltab + lbins ready

    const unsigned char* lt = ltab + pad;
    int ky = (br3(p & 7) << 4) | br4(p >> 3);
    int mky = (ky <= 64) ? ky : 128 - ky;
    int b3m = br3(m);
#pragma unroll
    for (int j = 0; j < 16; ++j) {
        int kx = (br4(j) << 3) + b3m;      // c16 output map
        int mkx = (kx <= 64) ? kx : 128 - kx;
        float pk = r[j].x * r[j].x + r[j].y * r[j].y;
        atomicAdd(&lbins[t & 7][lt[mkx * 65 + mky]], pk);
    }
    __syncthreads();
    if (t < 101) {
        float wz = (kz == 0 || kz == 64) ? 1.0f : 2.0f;
        float v = lbins[0][t] + lbins[1][t] + lbins[2][t] + lbins[3][t] +
                  lbins[4][t] + lbins[5][t] + lbins[6][t] + lbins[7][t];
        if (v != 0.0f) atomicAdd(&sums[f * 101 + t], v * (NORMF) * wz);
    }
}

// ---------------- Finalize: separate tiny kernel ----------------
__global__ __launch_bounds__(128) void k_finalize(const float* __restrict__ sums,
                                                  const int* __restrict__ counts,
                                                  float* __restrict__ out) {
    __shared__ double ssum[128];
    __shared__ int scnt[128];
    int k = threadIdx.x;
    double local = 0.0;
    int nloc = 0;
    if (k < KBINS) {
        int c = counts[k];
        if (c > 0) {
            double start, step, stop;
            bin_params(&start, &step, &stop);
            double e0 = bin_edge(k, start, step, stop);
            double e1 = bin_edge(k + 1, start, step, stop);
            float kc  = (float)(0.5 * (e0 + e1));
            float kc3 = kc * kc * kc;
            const float two_pi2 = (float)(2.0 * M_PI * M_PI);
            float cf = (float)c;
            for (int b = 0; b < 8; ++b) {
                float pm_p = sums[b * 101 + k] / cf;
                float pm_t = sums[(8 + b) * 101 + k] / cf;
                float dsq_p = pm_p * kc3 / two_pi2;
                float dsq_t = pm_t * kc3 / two_pi2;
                float d = fabsf(log10f(dsq_t) - log10f(dsq_p));
                local += (double)d;
            }
            nloc = 8;
        }
    }
    ssum[k] = local;
    scnt[k] = nloc;
    __syncthreads();
    for (int off = 64; off > 0; off >>= 1) {
        if (k < off) { ssum[k] += ssum[k + off]; scnt[k] += scnt[k + off]; }
        __syncthreads();
    }
    if (k == 0) out[0] = (float)(ssum[0] / (double)scnt[0]);
}

// ---------------- launch ----------------
extern "C" void kernel_launch(void* const* d_in, const int* in_sizes, int n_in,
                              void* d_out, int out_size, void* d_ws, size_t ws_size,
                              hipStream_t stream) {
    (void)in_sizes; (void)n_in; (void)out_size; (void)ws_size;
    const float* pred   = (const float*)d_in[0];
    const float* target = (const float*)d_in[1];
    float* out = (float*)d_out;
    char* ws = (char*)d_ws;

    float* sums        = (float*)(ws + WS_SUMS_OFF);   // [16][101]
    int* counts        = (int*)(ws + WS_CNT_OFF);      // [101]
    unsigned char* oct = (unsigned char*)(ws + WS_OCT_OFF);
    float2* A          = (float2*)(ws + WS_TRANS_OFF); // tiled layout per field

    hipMemsetAsync(ws, 0, 8192, stream);               // sums + counts (+ctr slot)

    // y==0: oct table (concurrent with zy); y>=1: zy planes for field y-1
    k_zy_oct<<<dim3(128, NFIELDS + 1), 512, 0, stream>>>(pred, target, A, oct, counts);
    k_fft_x_bin<<<dim3(65 * 4, NFIELDS), 256, 0, stream>>>(A, oct, sums);
    k_finalize<<<1, 128, 0, stream>>>(sums, counts, out);
}